// Round 1
// baseline (675.994 us; speedup 1.0000x reference)
//
#include <hip/hip_runtime.h>

// Problem: x [16, 512, 512, 32] f32 -> out [16, 512, 512, 1] f32
// out[b,h,w] = max over shifts S = {(0,0),(0,1),(1,0),(1,1),(0,2),(2,0),(2,2)}
//              of M[b, h-di, w-dj],  M = channel-max of x, OOB -> 0 (zero pad).
// Memory-bound: 537 MB read + 16.8 MB write -> ~88 us floor at 6.3 TB/s.

#define HH 512
#define WW 512
#define CC 32
#define TILE 64
#define REG (TILE + 2)   // 66: backward halo of 2 in h and w
#define LSTR REG         // LDS row stride (66); phase-2 lanes read consecutive
                         // addresses within a row -> conflict-free, no pad needed

__global__ __launch_bounds__(256) void maxassign2d_kernel(
    const float* __restrict__ x, float* __restrict__ out) {
  __shared__ float m[REG * LSTR];

  const int b  = blockIdx.z;
  const int h0 = blockIdx.y * TILE;
  const int w0 = blockIdx.x * TILE;
  const int tid = threadIdx.x;

  // ---- Phase 1: channel-max of x into LDS for the 66x66 region ----
  // Each region pixel = 32 contiguous f32 = 128 B = one cache line,
  // read as 8x float4 by one thread.
  for (int p = tid; p < REG * REG; p += 256) {
    const int rr = p / REG;
    const int cc = p - rr * REG;
    const int h = h0 + rr - 2;   // max: 448+65-2 = 511 < 512, only low side can OOB
    const int w = w0 + cc - 2;
    float v = 0.0f;              // pad value: zero joins the max at borders
    if (h >= 0 && w >= 0) {
      const float4* px =
          (const float4*)(x + (((size_t)b * HH + h) * WW + w) * CC);
      float4 a0 = px[0], a1 = px[1], a2 = px[2], a3 = px[3];
      float4 a4 = px[4], a5 = px[5], a6 = px[6], a7 = px[7];
      float m0 = fmaxf(fmaxf(a0.x, a0.y), fmaxf(a0.z, a0.w));
      float m1 = fmaxf(fmaxf(a1.x, a1.y), fmaxf(a1.z, a1.w));
      float m2 = fmaxf(fmaxf(a2.x, a2.y), fmaxf(a2.z, a2.w));
      float m3 = fmaxf(fmaxf(a3.x, a3.y), fmaxf(a3.z, a3.w));
      float m4 = fmaxf(fmaxf(a4.x, a4.y), fmaxf(a4.z, a4.w));
      float m5 = fmaxf(fmaxf(a5.x, a5.y), fmaxf(a5.z, a5.w));
      float m6 = fmaxf(fmaxf(a6.x, a6.y), fmaxf(a6.z, a6.w));
      float m7 = fmaxf(fmaxf(a7.x, a7.y), fmaxf(a7.z, a7.w));
      v = fmaxf(fmaxf(fmaxf(m0, m1), fmaxf(m2, m3)),
                fmaxf(fmaxf(m4, m5), fmaxf(m6, m7)));
    }
    m[rr * LSTR + cc] = v;
  }
  __syncthreads();

  // ---- Phase 2: 7-way backward-shift max over the LDS tile ----
  // Output (r,c) sits at region coord (r+2, c+2); shift (di,dj) reads
  // region (r+2-di, c+2-dj).
  for (int p = tid; p < TILE * TILE; p += 256) {
    const int r = p >> 6;
    const int c = p & (TILE - 1);
    const float* base = &m[r * LSTR + c];
    float v = base[2 * LSTR + 2];              // (0,0)
    v = fmaxf(v, base[2 * LSTR + 1]);          // (0,1)
    v = fmaxf(v, base[1 * LSTR + 2]);          // (1,0)
    v = fmaxf(v, base[1 * LSTR + 1]);          // (1,1)
    v = fmaxf(v, base[2 * LSTR + 0]);          // (0,2)
    v = fmaxf(v, base[0 * LSTR + 2]);          // (2,0)
    v = fmaxf(v, base[0 * LSTR + 0]);          // (2,2)
    out[((size_t)b * HH + (h0 + r)) * WW + (w0 + c)] = v;
  }
}

extern "C" void kernel_launch(void* const* d_in, const int* in_sizes, int n_in,
                              void* d_out, int out_size, void* d_ws, size_t ws_size,
                              hipStream_t stream) {
  const float* x = (const float*)d_in[0];
  float* out = (float*)d_out;
  const int B = in_sizes[0] / (HH * WW * CC);  // = 16
  dim3 grid(WW / TILE, HH / TILE, B);          // (8, 8, 16)
  maxassign2d_kernel<<<grid, 256, 0, stream>>>(x, out);
}